// Round 16
// baseline (1398.279 us; speedup 1.0000x reference)
//
#include <hip/hip_runtime.h>
#include <math.h>

#define BB 16
#define SS 128
#define DD 768
#define HH 12
#define DKK 64
#define DFFF 3072
#define NLL 6
#define SRCC 256

typedef short bf16x8 __attribute__((ext_vector_type(8)));
typedef float f32x4 __attribute__((ext_vector_type(4)));
typedef unsigned short us8 __attribute__((ext_vector_type(8)));
typedef unsigned short us4 __attribute__((ext_vector_type(4)));

__device__ __forceinline__ unsigned short f2bf(float f) {
  unsigned int u = __builtin_bit_cast(unsigned int, f);
  u = (u + 0x7fff + ((u >> 16) & 1)) >> 16;
  return (unsigned short)u;
}

#define GLOADLDS16(gp, lp)                                              \
  __builtin_amdgcn_global_load_lds(                                     \
      (const __attribute__((address_space(1))) void*)(gp),              \
      (__attribute__((address_space(3))) void*)(lp), 16, 0, 0)

// ---------------- LayerNorm f32-out (final) ----------------
__global__ __launch_bounds__(256) void ln_k(const float* __restrict__ x,
                                            const float* __restrict__ ga,
                                            const float* __restrict__ gb,
                                            float* __restrict__ out) {
  __shared__ float sm[8];
  int row = blockIdx.x;
  int t = threadIdx.x;
  const float* xr = x + (size_t)row * DD;
  float v0 = xr[t], v1 = xr[t + 256], v2 = xr[t + 512];
  float s = v0 + v1 + v2;
#pragma unroll
  for (int o = 32; o > 0; o >>= 1) s += __shfl_down(s, o);
  if ((t & 63) == 0) sm[t >> 6] = s;
  __syncthreads();
  float mean = (sm[0] + sm[1] + sm[2] + sm[3]) * (1.0f / (float)DD);
  float d0 = v0 - mean, d1 = v1 - mean, d2 = v2 - mean;
  float q = d0 * d0 + d1 * d1 + d2 * d2;
#pragma unroll
  for (int o = 32; o > 0; o >>= 1) q += __shfl_down(q, o);
  if ((t & 63) == 0) sm[4 + (t >> 6)] = q;
  __syncthreads();
  float var = (sm[4] + sm[5] + sm[6] + sm[7]) * (1.0f / (float)DD);
  float inv = 1.0f / sqrtf(var + 1e-6f);
  float* orow = out + (size_t)row * DD;
  orow[t]       = ga[t] * d0 * inv + gb[t];
  orow[t + 256] = ga[t + 256] * d1 * inv + gb[t + 256];
  orow[t + 512] = ga[t + 512] * d2 * inv + gb[t + 512];
}

// ---------------- LayerNorm bf16-out ----------------
__device__ __forceinline__ void lnb_body(const float* __restrict__ xr,
                                         const float* __restrict__ ga,
                                         const float* __restrict__ gb,
                                         unsigned short* __restrict__ orow,
                                         float* sm, int t) {
  float v0 = xr[t], v1 = xr[t + 256], v2 = xr[t + 512];
  float s = v0 + v1 + v2;
#pragma unroll
  for (int o = 32; o > 0; o >>= 1) s += __shfl_down(s, o);
  if ((t & 63) == 0) sm[t >> 6] = s;
  __syncthreads();
  float mean = (sm[0] + sm[1] + sm[2] + sm[3]) * (1.0f / (float)DD);
  float d0 = v0 - mean, d1 = v1 - mean, d2 = v2 - mean;
  float q = d0 * d0 + d1 * d1 + d2 * d2;
#pragma unroll
  for (int o = 32; o > 0; o >>= 1) q += __shfl_down(q, o);
  if ((t & 63) == 0) sm[4 + (t >> 6)] = q;
  __syncthreads();
  float var = (sm[4] + sm[5] + sm[6] + sm[7]) * (1.0f / (float)DD);
  float inv = 1.0f / sqrtf(var + 1e-6f);
  orow[t]       = f2bf(ga[t] * d0 * inv + gb[t]);
  orow[t + 256] = f2bf(ga[t + 256] * d1 * inv + gb[t + 256]);
  orow[t + 512] = f2bf(ga[t + 512] * d2 * inv + gb[t + 512]);
}

__global__ __launch_bounds__(256) void lnb_k(const float* __restrict__ x,
                                             const float* __restrict__ ga,
                                             const float* __restrict__ gb,
                                             unsigned short* __restrict__ out) {
  __shared__ float sm[8];
  int row = blockIdx.x;
  lnb_body(x + (size_t)row * DD, ga, gb, out + (size_t)row * DD, sm, threadIdx.x);
}

// two LN in one launch
__global__ __launch_bounds__(256) void lnb2_k(const float* __restrict__ x,
                                              const float* __restrict__ y,
                                              const float* __restrict__ gax,
                                              const float* __restrict__ gbx,
                                              const float* __restrict__ gay,
                                              const float* __restrict__ gby,
                                              unsigned short* __restrict__ ox,
                                              unsigned short* __restrict__ oy) {
  __shared__ float sm[8];
  int row = blockIdx.x;
  if (row < BB * SS)
    lnb_body(x + (size_t)row * DD, gax, gbx, ox + (size_t)row * DD, sm, threadIdx.x);
  else {
    row -= BB * SS;
    lnb_body(y + (size_t)row * DD, gay, gby, oy + (size_t)row * DD, sm, threadIdx.x);
  }
}

// ---------- 64k x 64n transpose tile: f32 [K][N] -> bf16 [N][K] ----------
__device__ __forceinline__ void tr_tile64(const float* __restrict__ s,
                                          unsigned short* __restrict__ d,
                                          int K, int N, int k0, int n0,
                                          float (*tl)[69], int t) {
#pragma unroll
  for (int i = 0; i < 4; i++) {
    int c = t + i * 256;
    int row = c >> 4, c4 = (c & 15) * 4;
    float4 v = *(const float4*)(s + (size_t)(k0 + row) * N + n0 + c4);
    tl[row][c4 + 0] = v.x; tl[row][c4 + 1] = v.y;
    tl[row][c4 + 2] = v.z; tl[row][c4 + 3] = v.w;
  }
  __syncthreads();
#pragma unroll
  for (int i = 0; i < 2; i++) {
    int c = t + i * 256;
    int n = c >> 3, kc = c & 7;
    us8 o;
#pragma unroll
    for (int j = 0; j < 8; j++) o[j] = f2bf(tl[kc * 8 + j][n]);
    *(us8*)(d + (size_t)(n0 + n) * K + k0 + kc * 8) = o;
  }
}

// ---- mega-upfront kernel: weight transposes (XCD-swizzled) + eob + emb/y + mask/bias ----
// [0,18816): transposes+eob (swizzled);  [18816,21888): embjoint;  [21888,22033): mask+bias.
__global__ __launch_bounds__(256) void wtx_k(
    const float* __restrict__ Wq, const float* __restrict__ Wk,
    const float* __restrict__ Wv, const float* __restrict__ Wo,
    const float* __restrict__ W1, const float* __restrict__ W2,
    const float* __restrict__ e_out,
    unsigned short* __restrict__ wqkv1A, unsigned short* __restrict__ wq2A,
    unsigned short* __restrict__ wkv2A, unsigned short* __restrict__ wqkv3A,
    unsigned short* __restrict__ wotA,
    unsigned short* __restrict__ w1tA, unsigned short* __restrict__ w2tA,
    unsigned short* __restrict__ eob,
    const int* __restrict__ trg, const float* __restrict__ emb,
    const float* __restrict__ alpha, const float* __restrict__ yp,
    float* __restrict__ x, float* __restrict__ y,
    int* __restrict__ rbuf,
    const float* __restrict__ bq, const float* __restrict__ bk,
    const float* __restrict__ bv, float* __restrict__ bqkv1,
    float* __restrict__ bkv2, float* __restrict__ bqkv3) {
  __shared__ float tl[64][69];
  const size_t M1 = (size_t)DD * DD;
  int rawbid = blockIdx.x;
  int t = threadIdx.x;
  if (rawbid < 18816) {
    int bid = (rawbid & 7) * 2352 + (rawbid >> 3);
    if (bid < 10368) {
      int mat = bid / 144, rem = bid % 144;
      int kt = rem / 12, nt = rem % 12;
      int l = mat / 12, m = mat % 12;
      size_t s3 = (size_t)l * 3 * M1;
      const float* s;
      unsigned short* d;
      switch (m) {
        case 0:  s = Wq + s3;          d = wqkv1A + l * 3 * M1;          break;
        case 1:  s = Wk + s3;          d = wqkv1A + l * 3 * M1 + M1;     break;
        case 2:  s = Wv + s3;          d = wqkv1A + l * 3 * M1 + 2 * M1; break;
        case 3:  s = Wq + s3 + M1;     d = wq2A + l * M1;                break;
        case 4:  s = Wk + s3 + M1;     d = wkv2A + l * 2 * M1;           break;
        case 5:  s = Wv + s3 + M1;     d = wkv2A + l * 2 * M1 + M1;      break;
        case 6:  s = Wq + s3 + 2 * M1; d = wqkv3A + l * 3 * M1;          break;
        case 7:  s = Wk + s3 + 2 * M1; d = wqkv3A + l * 3 * M1 + M1;     break;
        case 8:  s = Wv + s3 + 2 * M1; d = wqkv3A + l * 3 * M1 + 2 * M1; break;
        case 9:  s = Wo + s3;          d = wotA + l * 3 * M1;            break;
        case 10: s = Wo + s3 + M1;     d = wotA + l * 3 * M1 + M1;       break;
        default: s = Wo + s3 + 2 * M1; d = wotA + l * 3 * M1 + 2 * M1;   break;
      }
      tr_tile64(s, d, DD, DD, kt * 64, nt * 64, tl, t);
    } else if (bid < 13824) {
      int idx = bid - 10368;
      int l = idx / 576, rem = idx % 576;
      int kt = rem / 48, nt = rem % 48;
      tr_tile64(W1 + (size_t)l * DD * DFFF, w1tA + (size_t)l * DD * DFFF,
                DD, DFFF, kt * 64, nt * 64, tl, t);
    } else if (bid < 17280) {
      int idx = bid - 13824;
      int l = idx / 576, rem = idx % 576;
      int kt = rem / 12, nt = rem % 12;
      tr_tile64(W2 + (size_t)l * DFFF * DD, w2tA + (size_t)l * DFFF * DD,
                DFFF, DD, kt * 64, nt * 64, tl, t);
    } else {
      size_t base = (size_t)(bid - 17280) * 2048 + (size_t)t * 8;
      float4 a = *(const float4*)(e_out + base);
      float4 b = *(const float4*)(e_out + base + 4);
      us8 o;
      o[0] = f2bf(a.x); o[1] = f2bf(a.y); o[2] = f2bf(a.z); o[3] = f2bf(a.w);
      o[4] = f2bf(b.x); o[5] = f2bf(b.y); o[6] = f2bf(b.z); o[7] = f2bf(b.w);
      *(us8*)(eob + base) = o;
    }
  } else if (rawbid < 21888) {
    int z = rawbid - 18816;
    int half = (z >= 1536) ? 1 : 0;
    int idx = (z - half * 1536) * 256 + t;
    int c = idx % (DD / 4);
    int r = idx / (DD / 4);
    int s = r % SS;
    if (half == 0) {
      float al = alpha[0];
      float4 e = *(const float4*)(emb + (size_t)trg[r] * DD + c * 4);
      float coef = -logf(10000.0f) / (float)DD;
      float div0 = expf((float)(4 * c) * coef);
      float div1 = expf((float)(4 * c + 2) * coef);
      float s0, c0, s1, c1;
      sincosf((float)s * div0, &s0, &c0);
      sincosf((float)s * div1, &s1, &c1);
      float4 o;
      o.x = e.x + al * s0; o.y = e.y + al * c0;
      o.z = e.z + al * s1; o.w = e.w + al * c1;
      *(float4*)(x + (size_t)r * DD + c * 4) = o;
    } else {
      *(float4*)(y + (size_t)r * DD + c * 4) = *(const float4*)(yp + (size_t)s * DD + c * 4);
    }
  } else {
    int mbid = rawbid - 21888;
    if (mbid == 0) {
      __shared__ int first[BB];
      if (t < BB) first[t] = 0x7fffffff;
      __syncthreads();
      int b = t >> 4, p0 = (t & 15) * 8;
      int loc = 0x7fffffff;
#pragma unroll
      for (int i = 0; i < 8; i++) {
        if (trg[b * SS + p0 + i] == 0) { loc = p0 + i; break; }
      }
      atomicMin(&first[b], loc);
      __syncthreads();
      if (t == 0) {
        int cmin = 0x7fffffff;
        int cm[BB];
        for (int bb = 0; bb < BB; bb++) {
          int start = (first[bb] == 0x7fffffff) ? 0 : first[bb];
          int c = (start == 0) ? (SS + 1) : start;
          cmin = min(cmin, c);
          cm[bb] = cmin;
        }
        for (int bb = 0; bb < BB; bb++) rbuf[bb] = cm[min(bb, BB - 2)];
      }
      return;
    }
    int i = (mbid - 1) * 256 + t;
    if (i >= NLL * 6144) return;
    int l = i / 6144, j = i - l * 6144;
    if (j < 2304) {
      int s = j / 768, c = j - s * 768;
      const float* src = (s == 0) ? bq : (s == 1 ? bk : bv);
      bqkv1[l * 2304 + j] = src[(l * 3 + 0) * 768 + c];
    } else if (j < 3840) {
      int jj = j - 2304;
      int s = jj / 768, c = jj - s * 768;
      bkv2[l * 1536 + jj] = ((s == 0) ? bk : bv)[(l * 3 + 1) * 768 + c];
    } else {
      int jj = j - 3840;
      int s = jj / 768, c = jj - s * 768;
      const float* src = (s == 0) ? bq : (s == 1 ? bk : bv);
      bqkv3[l * 2304 + jj] = src[(l * 3 + 2) * 768 + c];
    }
  }
}

// ============ GEMM core macro: BK=64, two stacked 32-wide panels ============
#define GEMM_BODY64(BM, A, Bt, m0, n0, KK)                                    \
  constexpr int FM = (BM) / 32;                                               \
  constexpr int HB = (BM) / 2;                                                \
  int wave = t >> 6, lane = t & 63;                                           \
  int wm = wave >> 1, wn = wave & 1;                                          \
  int l15 = lane & 15, lhi = lane >> 4;                                       \
  f32x4 acc[FM][2] = {};                                                      \
  int aRow = t >> 2, aC8 = (t & 3) * 8;                                       \
  const unsigned short* Ab = (A) + (size_t)(m0) * (KK) + aC8;                 \
  const unsigned short* Bb = (Bt) + (size_t)(n0) * (KK) + aC8;                \
  int aOff0 = (wm * HB + l15) * 32 + lhi * 8;                                 \
  int bOff0 = (wn * 32 + l15) * 32 + lhi * 8;                                 \
  for (int k0 = 0; k0 < (KK); k0 += 64) {                                     \
    _Pragma("unroll")                                                         \
    for (int p = 0; p < 2; p++) {                                             \
      _Pragma("unroll")                                                       \
      for (int h = 0; h < (BM) / 64; h++)                                     \
        GLOADLDS16(Ab + (size_t)(h * 64 + aRow) * (KK) + k0 + p * 32,         \
                   As + p * ((BM) * 32) + h * 2048 + wave * 512);             \
      GLOADLDS16(Bb + (size_t)aRow * (KK) + k0 + p * 32,                      \
                 Bs + p * 2048 + wave * 512);                                 \
    }                                                                         \
    __syncthreads();                                                          \
    _Pragma("unroll")                                                         \
    for (int p = 0; p < 2; p++) {                                             \
      bf16x8 aF[FM], bF[2];                                                   \
      _Pragma("unroll")                                                       \
      for (int fm = 0; fm < FM; fm++)                                         \
        aF[fm] = *(const bf16x8*)(As + p * ((BM) * 32) + aOff0 + fm * 16 * 32);\
      _Pragma("unroll")                                                       \
      for (int fn = 0; fn < 2; fn++)                                          \
        bF[fn] = *(const bf16x8*)(Bs + p * 2048 + bOff0 + fn * 16 * 32);      \
      _Pragma("unroll")                                                       \
      for (int fm = 0; fm < FM; fm++)                                         \
        _Pragma("unroll")                                                     \
        for (int fn = 0; fn < 2; fn++)                                        \
          acc[fm][fn] = __builtin_amdgcn_mfma_f32_16x16x32_bf16(              \
              aF[fm], bF[fn], acc[fm][fn], 0, 0, 0);                          \
    }                                                                         \
    __syncthreads();                                                          \
  }                                                                           \
  int lcol = l15, lrow4 = lhi * 4;

// head-major store of one fragment column (4 rows) to hd with shift sh
__device__ __forceinline__ void hm_store(unsigned short* hd, int sh, int vt,
                                         int rowb, int colr, const f32x4& a,
                                         float bv) {
  int hh = colr >> 6, dd = colr & 63;
  int bb = rowb >> sh, ssb = rowb & ((1 << sh) - 1);
  if (vt) {
    size_t idx = (((size_t)bb * HH + hh) * 64 + dd) * (size_t)(1 << sh) + ssb;
    us4 pk;
#pragma unroll
    for (int r = 0; r < 4; r++) pk[r] = f2bf(a[r] + bv);
    *(us4*)(hd + idx) = pk;
  } else {
    size_t base = ((((size_t)bb * HH + hh) << sh) + ssb) * 64 + dd;
#pragma unroll
    for (int r = 0; r < 4; r++) hd[base + (size_t)r * 64] = f2bf(a[r] + bv);
  }
}

// ------- generic mgemm: flat 1D grid, XCD-chunked by-fastest swizzle -------
// Grid = (N/64)*(M/BM), must be %8==0. Each XCD gets contiguous nf range covering
// all m-tiles for a few bx -> weight panel read by ONE XCD (B-panel L2 reuse).
template <int BM>
__global__ __launch_bounds__(256) void mgemm_k(
    const unsigned short* __restrict__ A0, const unsigned short* __restrict__ A1,
    const unsigned short* __restrict__ Bt, const float* __restrict__ bias,
    const float* __restrict__ res, void* __restrict__ C,
    unsigned short* __restrict__ hd0, unsigned short* __restrict__ hd1,
    unsigned short* __restrict__ hd2,
    int sh0, int sh1, int sh2, int M, int N, int K, int flags, int vtbits) {
  __shared__ unsigned short As[2 * BM * 32];
  __shared__ unsigned short Bs[2 * 64 * 32];
  int t = threadIdx.x;
  int G = (N / 64) * (M / BM);
  int flat = blockIdx.x;
  int nf = (flat & 7) * (G >> 3) + (flat >> 3);   // bijective XCD chunking
  int MT = M / BM;
  int by = nf % MT, bx = nf / MT;                 // by fastest -> B-panel reuse
  int m0 = by * BM, n0 = bx * 64;
  int seg = n0 / 768;
  const unsigned short* A = (seg == 0) ? A0 : A1;
  GEMM_BODY64(BM, A, Bt, m0, n0, K)
  bool hm = (flags & 4) != 0;
  unsigned short* hd = nullptr;
  int sh = 0, segBase = seg * 768, vtseg = 0;
  if (hm) {
    hd = (seg == 0) ? hd0 : (seg == 1 ? hd1 : hd2);
    sh = (seg == 0) ? sh0 : (seg == 1 ? sh1 : sh2);
    vtseg = (vtbits >> seg) & 1;
  }
#pragma unroll
  for (int fm = 0; fm < FM; fm++) {
#pragma unroll
    for (int fn = 0; fn < 2; fn++) {
      int col = n0 + wn * 32 + fn * 16 + lcol;
      float bv = bias[col];
      int rowb = m0 + wm * HB + fm * 16 + lrow4;
      if (hm) {
        hm_store(hd, sh, vtseg, rowb, col - segBase, acc[fm][fn], bv);
      } else {
#pragma unroll
        for (int r = 0; r < 4; r++) {
          int row = rowb + r;
          float v = acc[fm][fn][r] + bv;
          size_t idx = (size_t)row * N + col;
          if (res) v += res[idx];
          if (flags & 1) v = fmaxf(v, 0.f);
          if (flags & 2) ((unsigned short*)C)[idx] = f2bf(v);
          else ((float*)C)[idx] = v;
        }
      }
    }
  }
}

// ---------------- all-layer KV2 projection: 128x64 tile, BK=64, XCD swizzle -----
__global__ __launch_bounds__(256) void kv2all_k(
    const unsigned short* __restrict__ eob, const unsigned short* __restrict__ wkv2A,
    const float* __restrict__ bkv2,
    unsigned short* __restrict__ khb2A, unsigned short* __restrict__ vthb2A) {
  __shared__ unsigned short As[2 * 128 * 32];
  __shared__ unsigned short Bs[2 * 64 * 32];
  const size_t M1 = (size_t)DD * DD;
  const size_t KVS = (size_t)BB * HH * SRCC * DKK;
  int t = threadIdx.x;
  int flat = blockIdx.x;                      // 4608 = 8 x 576
  int nf = (flat & 7) * 576 + (flat >> 3);    // bijective XCD chunking
  int bx = nf % 24;
  int rem = nf / 24;
  int by = rem & 31;
  int l = rem >> 5;
  int m0 = by * 128, n0 = bx * 64;
  const unsigned short* Bt = wkv2A + (size_t)l * 2 * M1;
  const float* bias = bkv2 + l * 1536;
  GEMM_BODY64(128, eob, Bt, m0, n0, 768)
  int seg = n0 / 768;
  unsigned short* hd = (seg == 0) ? khb2A + (size_t)l * KVS : vthb2A + (size_t)l * KVS;
  int segBase = seg * 768;
#pragma unroll
  for (int fm = 0; fm < FM; fm++) {
#pragma unroll
    for (int fn = 0; fn < 2; fn++) {
      int col = n0 + wn * 32 + fn * 16 + lcol;
      int rowb = m0 + wm * HB + fm * 16 + lrow4;
      hm_store(hd, 8, seg, rowb, col - segBase, acc[fm][fn], bias[col]);
    }
  }
}

// -------- batched qkv1 + q2, flat 768 grid, XCD-chunked by-fastest swizzle --------
__global__ __launch_bounds__(256) void qkvq_k(
    const unsigned short* __restrict__ x2b, const unsigned short* __restrict__ y1b,
    const unsigned short* __restrict__ Bqkv, const unsigned short* __restrict__ Bq2,
    const float* __restrict__ bias1, const float* __restrict__ bias2,
    unsigned short* __restrict__ qhb, unsigned short* __restrict__ khb,
    unsigned short* __restrict__ vthb, unsigned short* __restrict__ qhb2) {
  __shared__ unsigned short As[2 * 128 * 32];
  __shared__ unsigned short Bs[2 * 64 * 32];
  int t = threadIdx.x;
  int flat = blockIdx.x;
  int nf = (flat & 7) * 96 + (flat >> 3);     // 768 = 8 x 96
  bool j1 = nf >= 576;
  int bx, by;
  const unsigned short *A, *Bt;
  const float* bias;
  if (!j1) { int b2 = nf; by = b2 % 16; bx = b2 / 16; A = x2b; Bt = Bqkv; bias = bias1; }
  else { int b2 = nf - 576; by = b2 % 16; bx = b2 / 16; A = y1b; Bt = Bq2; bias = bias2; }
  int m0 = by * 128, n0 = bx * 64;
  GEMM_BODY64(128, A, Bt, m0, n0, 768)
  int seg = j1 ? 0 : (n0 / 768);
  unsigned short* hd = j1 ? qhb2 : (seg == 0 ? qhb : (seg == 1 ? khb : vthb));
  int vt = (!j1 && seg == 2) ? 1 : 0;
  int segBase = seg * 768;
#pragma unroll
  for (int fm = 0; fm < FM; fm++) {
#pragma unroll
    for (int fn = 0; fn < 2; fn++) {
      int col = n0 + wn * 32 + fn * 16 + lcol;
      int rowb = m0 + wm * HB + fm * 16 + lrow4;
      hm_store(hd, 7, vt, rowb, col - segBase, acc[fm][fn], bias[col]);
    }
  }
}

// ---- batched wo1 + wo2, flat 768 grid, XCD-chunked by-fastest swizzle ----
__global__ __launch_bounds__(256) void wob_k(
    const unsigned short* __restrict__ ctx1b, const unsigned short* __restrict__ ctx2b,
    const unsigned short* __restrict__ Bt0, const unsigned short* __restrict__ Bt1,
    const float* __restrict__ bo0, const float* __restrict__ bo1,
    float* __restrict__ x, float* __restrict__ y) {
  __shared__ unsigned short As[2 * 64 * 32];
  __shared__ unsigned short Bs[2 * 64 * 32];
  int t = threadIdx.x;
  int flat = blockIdx.x;
  int nf = (flat & 7) * 96 + (flat >> 3);     // 768 = 8 x 96
  bool j1 = nf >= 384;
  int b2 = j1 ? nf - 384 : nf;
  int by = b2 % 32, bx = b2 / 32;             // by fastest -> Wo panel reuse
  const unsigned short* A = j1 ? ctx2b : ctx1b;
  const unsigned short* Bt = j1 ? Bt1 : Bt0;
  const float* bias = j1 ? bo1 : bo0;
  float* C = j1 ? y : x;
  int m0 = by * 64, n0 = bx * 64;
  GEMM_BODY64(64, A, Bt, m0, n0, 768)
#pragma unroll
  for (int fm = 0; fm < FM; fm++) {
#pragma unroll
    for (int fn = 0; fn < 2; fn++) {
      int col = n0 + wn * 32 + fn * 16 + lcol;
      float bv = bias[col];
      int rowb = m0 + wm * HB + fm * 16 + lrow4;
#pragma unroll
      for (int r = 0; r < 4; r++) {
        size_t idx = (size_t)(rowb + r) * DD + col;
        C[idx] += acc[fm][fn][r] + bv;
      }
    }
  }
}

// ---------------- MFMA flash attention body (R8-proven inner loops) --------------
template <int SK>
__device__ __forceinline__ void attn_body(
    const unsigned short* __restrict__ qh, const unsigned short* __restrict__ kh,
    const unsigned short* __restrict__ vth, unsigned short* __restrict__ ctxb,
    int mode, const int* __restrict__ rbuf, const int* __restrict__ smask,
    unsigned short* __restrict__ kvb, unsigned short* __restrict__ pbuf,
    int qhalf, int h, int b) {
  constexpr int NPH = SK / 128;
  constexpr int NF = SK / 16;
  int t = threadIdx.x;
  int wave = t >> 6, lane = t & 63;
  int l15 = lane & 15, lhi = lane >> 4;
  int qrow0 = qhalf * 64 + wave * 16;
  size_t bh = (size_t)b * HH + h;
  bf16x8 aQ[2];
#pragma unroll
  for (int ks = 0; ks < 2; ks++)
    aQ[ks] = *(const bf16x8*)(qh + (bh * SS + qrow0 + l15) * 64 + ks * 32 + lhi * 8);
  f32x4 accS[NF] = {};
  const unsigned short* kbase = kh + bh * SK * 64;
  for (int ph = 0; ph < NPH; ph++) {
    if (ph) __syncthreads();
    {
      int c0 = t * 4;
#pragma unroll
      for (int i = 0; i < 4; i++) {
        int c = c0 + i, row = c >> 3, co = (c & 7) * 8;
        *(us8*)&kvb[row * 72 + co] = *(const us8*)(kbase + (size_t)(ph * 128 + row) * 64 + co);
      }
    }
    __syncthreads();
#pragma unroll
    for (int kf = 0; kf < 8; kf++) {
      int gf = ph * 8 + kf;
#pragma unroll
      for (int ks = 0; ks < 2; ks++) {
        bf16x8 bK = *(const bf16x8*)(&kvb[(kf * 16 + l15) * 72 + ks * 32 + lhi * 8]);
        accS[gf] = __builtin_amdgcn_mfma_f32_16x16x32_bf16(aQ[ks], bK, accS[gf], 0, 0, 0);
      }
    }
  }
  int rcut = (mode == 0) ? rbuf[b] : 0;
#pragma unroll
  for (int r = 0; r < 4; r++) {
    int qg = qrow0 + lhi * 4 + r;
    float mx = -3.4e38f;
#pragma unroll
    for (int gf = 0; gf < NF; gf++) {
      int k = gf * 16 + l15;
      float s = accS[gf][r] * 0.125f;
      bool keep = true;
      if (mode == 0) keep = (k <= qg) && (qg < rcut);
      else if (mode == 1) keep = (smask[b * SRCC + k] != 0);
      s = keep ? s : -1e9f;
      accS[gf][r] = s;
      mx = fmaxf(mx, s);
    }
#pragma unroll
    for (int o = 1; o < 16; o <<= 1) mx = fmaxf(mx, __shfl_xor(mx, o));
    float sum = 0.f;
#pragma unroll
    for (int gf = 0; gf < NF; gf++) {
      float e = expf(accS[gf][r] - mx);
      accS[gf][r] = e;
      sum += e;
    }
#pragma unroll
    for (int o = 1; o < 16; o <<= 1) sum += __shfl_xor(sum, o);
    float rinv = 1.0f / sum;
#pragma unroll
    for (int gf = 0; gf < NF; gf++) accS[gf][r] *= rinv;
  }
#pragma unroll
  for (int gf = 0; gf < NF; gf++) {
#pragma unroll
    for (int r = 0; r < 4; r++) {
      int ql = wave * 16 + lhi * 4 + r;
      pbuf[ql * (SK + 8) + gf * 16 + l15] = f2bf(accS[gf][r]);
    }
  }
  __syncthreads();
  f32x4 accO[4] = {};
  const unsigned short* vbase = vth + bh * 64 * SK;
  for (int ph = 0; ph < NPH; ph++) {
    if (ph) __syncthreads();
    {
      int c0 = t * 4;
#pragma unroll
      for (int i = 0; i < 4; i++) {
        int c = c0 + i, row = c >> 4, co = (c & 15) * 8;
        *(us8*)&kvb[row * 136 + co] = *(const us8*)(vbase + (size_t)row * SK + ph * 128 + co);
      }
    }
    __syncthreads();
#pragma unroll
    for (int ks = 0; ks < 4; ks++) {
      bf16x8 aP = *(const bf16x8*)(&pbuf[(wave * 16 + l15) * (SK + 8) + ph * 128 + ks * 32 + lhi * 8]);
#pragma unroll
      for (int nf = 0; nf < 4; nf++) {
        bf16x8 bV = *(const bf16x8*)(&kvb[(nf * 16 + l15) * 136 + ks * 32 + lhi * 8]);
        accO[nf] = __builtin_amdgcn_mfma_f32_16x16x32_bf16(aP, bV, accO[nf], 0, 0, 0);
      }
    }
  }
#pragma unroll
  for (int nf = 0; nf < 4; nf++) {
#pragma unroll
    for (int r = 0; r < 4; r++) {
      int qg = qrow0 + lhi * 4 + r;
      ctxb[((size_t)b * SS + qg) * DD + h * 64 + nf * 16 + l15] = f2bf(accO[nf][r]);
    }
  }
}

// single-stream attention (step 8)
template <int SK>
__global__ __launch_bounds__(256) void attn3_k(const unsigned short* __restrict__ qh,
                                               const unsigned short* __restrict__ kh,
                                               const unsigned short* __restrict__ vth,
                                               unsigned short* __restrict__ ctxb, int mode,
                                               const int* __restrict__ rbuf,
                                               const int* __restrict__ smask) {
  __shared__ unsigned short kvb[128 * 72];
  __shared__ unsigned short pbuf[64 * (SK + 8)];
  attn_body<SK>(qh, kh, vth, ctxb, mode, rbuf, smask, kvb, pbuf,
                blockIdx.x, blockIdx.y, blockIdx.z);
}

// merged self(SK=128, mode0) + cross(SK=256, mode1): 768 blocks = 3/CU exactly.
__global__ __launch_bounds__(256) void attnboth_k(
    const unsigned short* __restrict__ qh1, const unsigned short* __restrict__ kh1,
    const unsigned short* __restrict__ vth1,
    const unsigned short* __restrict__ qh2, const unsigned short* __restrict__ kh2,
    const unsigned short* __restrict__ vth2,
    unsigned short* __restrict__ ctx1b, unsigned short* __restrict__ ctx2b,
    const int* __restrict__ rbuf, const int* __restrict__ smask) {
  __shared__ unsigned short kvb[128 * 72];
  __shared__ unsigned short pbuf[64 * (SRCC + 8)];
  int bid = blockIdx.x;
  if (bid < 384) {
    int qhalf = bid & 1, rest = bid >> 1;
    int h = rest % HH, b = rest / HH;
    attn_body<SRCC>(qh2, kh2, vth2, ctx2b, 1, nullptr, smask, kvb, pbuf, qhalf, h, b);
  } else {
    int b2 = bid - 384;
    int qhalf = b2 & 1, rest = b2 >> 1;
    int h = rest % HH, b = rest / HH;
    attn_body<SS>(qh1, kh1, vth1, ctx1b, 0, rbuf, nullptr, kvb, pbuf, qhalf, h, b);
  }
}

// ---------------- launch ----------------
extern "C" void kernel_launch(void* const* d_in, const int* in_sizes, int n_in,
                              void* d_out, int out_size, void* d_ws, size_t ws_size,
                              hipStream_t stream) {
  const int*   trg   = (const int*)d_in[0];
  const float* e_out = (const float*)d_in[1];
  const int*   smask = (const int*)d_in[2];
  const float* emb   = (const float*)d_in[3];
  const float* ypar  = (const float*)d_in[4];
  const float* alpha = (const float*)d_in[5];
  const float* Wq = (const float*)d_in[6];
  const float* Wk = (const float*)d_in[7];
  const float* Wv = (const float*)d_in[8];
  const float* Wo = (const float*)d_in[9];
  const float* bq = (const float*)d_in[10];
  const float* bk = (const float*)d_in[11];
  const float* bv = (const float*)d_in[12];
  const float* bo = (const float*)d_in[13];
  const float* W1 = (const float*)d_in[14];
  const float* b1 = (const float*)d_in[15];
  const float* W2 = (const float*)d_in[16];
  const float* b2 = (const float*)d_in[17];
  const float* lna = (const float*)d_in[18];
  const float* lnbp = (const float*)d_in[19];
  const float* fa = (const float*)d_in[20];
  const float* fb = (const float*)d_in[21];
  float* out = (float*)d_out;

  float* ws = (float*)d_ws;
  size_t off = 0;
  auto alloc = [&](size_t n) { float* p = ws + off; off += n; return p; };
  const size_t M1 = (size_t)DD * DD;
  const size_t KVS = (size_t)BB * HH * SRCC * DKK;
  int* rbuf  = (int*)alloc(64);
  float* x   = alloc((size_t)BB * SS * DD);
  float* y   = alloc((size_t)BB * SS * DD);
  float* bqkv1 = alloc((size_t)NLL * 2304);
  float* bkv2  = alloc((size_t)NLL * 1536);
  float* bqkv3 = alloc((size_t)NLL * 2304);
  unsigned short* qhb   = (unsigned short*)alloc((size_t)BB * HH * SS * DKK / 2);
  unsigned short* qhb2  = (unsigned short*)alloc((size_t)BB * HH * SS * DKK / 2);
  unsigned short* khb   = (unsigned short*)alloc((size_t)BB * HH * SS * DKK / 2);
  unsigned short* vthb  = (unsigned short*)alloc((size_t)BB * HH * SS * DKK / 2);
  unsigned short* khb2A  = (unsigned short*)alloc((size_t)NLL * KVS / 2);
  unsigned short* vthb2A = (unsigned short*)alloc((size_t)NLL * KVS / 2);
  unsigned short* x2b   = (unsigned short*)alloc((size_t)BB * SS * DD / 2);
  unsigned short* y3b   = (unsigned short*)alloc((size_t)BB * SS * DD / 2);
  unsigned short* ctx1b = (unsigned short*)alloc((size_t)BB * SS * DD / 2);
  unsigned short* ctx2b = (unsigned short*)alloc((size_t)BB * SS * DD / 2);
  unsigned short* midb  = (unsigned short*)alloc((size_t)BB * SS * DFFF / 2);
  unsigned short* eob   = (unsigned short*)alloc((size_t)BB * SRCC * DD / 2);
  unsigned short* wqkv1A = (unsigned short*)alloc((size_t)NLL * 3 * M1 / 2);
  unsigned short* wq2A   = (unsigned short*)alloc((size_t)NLL * M1 / 2);
  unsigned short* wkv2A  = (unsigned short*)alloc((size_t)NLL * 2 * M1 / 2);
  unsigned short* wqkv3A = (unsigned short*)alloc((size_t)NLL * 3 * M1 / 2);
  unsigned short* wotA   = (unsigned short*)alloc((size_t)NLL * 3 * M1 / 2);
  unsigned short* w1tA   = (unsigned short*)alloc((size_t)NLL * DD * DFFF / 2);
  unsigned short* w2tA   = (unsigned short*)alloc((size_t)NLL * DFFF * DD / 2);
  if (ws_size < off * sizeof(float)) return;

  // mega upfront kernel: transposes (XCD-swizzled) + eob + emb/y init + mask/bias
  wtx_k<<<22033, 256, 0, stream>>>(Wq, Wk, Wv, Wo, W1, W2, e_out,
                                   wqkv1A, wq2A, wkv2A, wqkv3A, wotA, w1tA, w2tA, eob,
                                   trg, emb, alpha, ypar, x, y, rbuf,
                                   bq, bk, bv, bqkv1, bkv2, bqkv3);
  kv2all_k<<<4608, 256, 0, stream>>>(eob, wkv2A, bkv2, khb2A, vthb2A);

  auto MG128 = [&](const unsigned short* A0, const unsigned short* A1, int M, int K,
                   const unsigned short* Bt, int N, const float* bias, const float* res,
                   void* C, unsigned short* h0, unsigned short* h1, unsigned short* h2,
                   int s0, int s1, int s2, int flags, int vtb) {
    mgemm_k<128><<<(N / 64) * (M / 128), 256, 0, stream>>>(A0, A1, Bt, bias, res, C,
                                                           h0, h1, h2, s0, s1, s2, M, N, K, flags, vtb);
  };
  auto MG64 = [&](const unsigned short* A0, int M, int K,
                  const unsigned short* Bt, int N, const float* bias, const float* res,
                  void* C, unsigned short* h0, int s0, int flags, int vtb) {
    mgemm_k<64><<<(N / 64) * (M / 64), 256, 0, stream>>>(A0, A0, Bt, bias, res, C,
                                                         h0, nullptr, nullptr, s0, 0, 0, M, N, K, flags, vtb);
  };
  const dim3 agrid(SS / 64, HH, BB);

  for (int l = 0; l < NLL; l++) {
    const float* lA = lna + (size_t)l * 5 * DD;
    const float* lB = lnbp + (size_t)l * 5 * DD;
    // 1) LN(x,slot0) + LN(y,slot1)
    lnb2_k<<<2 * BB * SS, 256, 0, stream>>>(x, y, lA, lB, lA + DD, lB + DD, x2b, y3b);
    // 2) qkv1 + q2 batched (swizzled flat grid)
    qkvq_k<<<768, 256, 0, stream>>>(x2b, y3b, wqkv1A + l * 3 * M1, wq2A + l * M1,
                                    bqkv1 + l * 2304, bq + ((size_t)l * 3 + 1) * DD,
                                    qhb, khb, vthb, qhb2);
    // 3+4) self-attn + cross-attn in ONE launch
    attnboth_k<<<768, 256, 0, stream>>>(qhb, khb, vthb,
                                        qhb2, khb2A + l * KVS, vthb2A + l * KVS,
                                        ctx1b, ctx2b, rbuf, smask);
    // 5) wo1 + wo2 batched (swizzled flat grid)
    wob_k<<<768, 256, 0, stream>>>(ctx1b, ctx2b, wotA + l * 3 * M1, wotA + l * 3 * M1 + M1,
                                   bo + (size_t)l * 3 * DD, bo + ((size_t)l * 3 + 1) * DD, x, y);
    // 6) LN(x,slot2) + LN(y,slot3)
    lnb2_k<<<2 * BB * SS, 256, 0, stream>>>(x, y, lA + 2 * DD, lB + 2 * DD,
                                            lA + 3 * DD, lB + 3 * DD, x2b, y3b);
    // 7) qkv3 (segmented A: x2b | y3b)
    MG128(x2b, y3b, BB * SS, DD, wqkv3A + l * 3 * M1, 2304, bqkv3 + l * 2304, nullptr,
          nullptr, qhb, khb, vthb, 7, 7, 7, 4, 0b100);
    // 8) cross-attn x<-ln(y), no mask
    attn3_k<SS><<<agrid, 256, 0, stream>>>(qhb, khb, vthb, ctx1b, 2, nullptr, nullptr);
    // 9) wo3
    MG64(ctx1b, BB * SS, DD, wotA + l * 3 * M1 + 2 * M1, DD, bo + ((size_t)l * 3 + 2) * DD,
         x, x, nullptr, 0, 0, 0);
    // 10) LN(x,slot4)
    lnb_k<<<BB * SS, 256, 0, stream>>>(x, lA + 4 * DD, lB + 4 * DD, x2b);
    // 11) FFN1 (relu, bf16 out)
    MG128(x2b, x2b, BB * SS, DD, w1tA + (size_t)l * DD * DFFF, DFFF, b1 + (size_t)l * DFFF,
          nullptr, midb, nullptr, nullptr, nullptr, 0, 0, 0, 3, 0);
    // 12) FFN2 (K=3072, res x)
    MG64(midb, BB * SS, DFFF, w2tA + (size_t)l * DFFF * DD, DD, b2 + (size_t)l * DD, x, x,
         nullptr, 0, 0, 0);
  }
  ln_k<<<BB * SS, 256, 0, stream>>>(x, fa, fb, out);
}

// Round 17
// 1345.223 us; speedup vs baseline: 1.0394x; 1.0394x over previous
//
#include <hip/hip_runtime.h>
#include <math.h>

#define BB 16
#define SS 128
#define DD 768
#define HH 12
#define DKK 64
#define DFFF 3072
#define NLL 6
#define SRCC 256

typedef short bf16x8 __attribute__((ext_vector_type(8)));
typedef float f32x4 __attribute__((ext_vector_type(4)));
typedef unsigned short us8 __attribute__((ext_vector_type(8)));
typedef unsigned short us4 __attribute__((ext_vector_type(4)));

__device__ __forceinline__ unsigned short f2bf(float f) {
  unsigned int u = __builtin_bit_cast(unsigned int, f);
  u = (u + 0x7fff + ((u >> 16) & 1)) >> 16;
  return (unsigned short)u;
}

#define GLOADLDS16(gp, lp)                                              \
  __builtin_amdgcn_global_load_lds(                                     \
      (const __attribute__((address_space(1))) void*)(gp),              \
      (__attribute__((address_space(3))) void*)(lp), 16, 0, 0)

// ---------------- LayerNorm f32-out (final) ----------------
__global__ __launch_bounds__(256) void ln_k(const float* __restrict__ x,
                                            const float* __restrict__ ga,
                                            const float* __restrict__ gb,
                                            float* __restrict__ out) {
  __shared__ float sm[8];
  int row = blockIdx.x;
  int t = threadIdx.x;
  const float* xr = x + (size_t)row * DD;
  float v0 = xr[t], v1 = xr[t + 256], v2 = xr[t + 512];
  float s = v0 + v1 + v2;
#pragma unroll
  for (int o = 32; o > 0; o >>= 1) s += __shfl_down(s, o);
  if ((t & 63) == 0) sm[t >> 6] = s;
  __syncthreads();
  float mean = (sm[0] + sm[1] + sm[2] + sm[3]) * (1.0f / (float)DD);
  float d0 = v0 - mean, d1 = v1 - mean, d2 = v2 - mean;
  float q = d0 * d0 + d1 * d1 + d2 * d2;
#pragma unroll
  for (int o = 32; o > 0; o >>= 1) q += __shfl_down(q, o);
  if ((t & 63) == 0) sm[4 + (t >> 6)] = q;
  __syncthreads();
  float var = (sm[4] + sm[5] + sm[6] + sm[7]) * (1.0f / (float)DD);
  float inv = 1.0f / sqrtf(var + 1e-6f);
  float* orow = out + (size_t)row * DD;
  orow[t]       = ga[t] * d0 * inv + gb[t];
  orow[t + 256] = ga[t + 256] * d1 * inv + gb[t + 256];
  orow[t + 512] = ga[t + 512] * d2 * inv + gb[t + 512];
}

// ---------------- LayerNorm bf16-out ----------------
__device__ __forceinline__ void lnb_body(const float* __restrict__ xr,
                                         const float* __restrict__ ga,
                                         const float* __restrict__ gb,
                                         unsigned short* __restrict__ orow,
                                         float* sm, int t) {
  float v0 = xr[t], v1 = xr[t + 256], v2 = xr[t + 512];
  float s = v0 + v1 + v2;
#pragma unroll
  for (int o = 32; o > 0; o >>= 1) s += __shfl_down(s, o);
  if ((t & 63) == 0) sm[t >> 6] = s;
  __syncthreads();
  float mean = (sm[0] + sm[1] + sm[2] + sm[3]) * (1.0f / (float)DD);
  float d0 = v0 - mean, d1 = v1 - mean, d2 = v2 - mean;
  float q = d0 * d0 + d1 * d1 + d2 * d2;
#pragma unroll
  for (int o = 32; o > 0; o >>= 1) q += __shfl_down(q, o);
  if ((t & 63) == 0) sm[4 + (t >> 6)] = q;
  __syncthreads();
  float var = (sm[4] + sm[5] + sm[6] + sm[7]) * (1.0f / (float)DD);
  float inv = 1.0f / sqrtf(var + 1e-6f);
  orow[t]       = f2bf(ga[t] * d0 * inv + gb[t]);
  orow[t + 256] = f2bf(ga[t + 256] * d1 * inv + gb[t + 256]);
  orow[t + 512] = f2bf(ga[t + 512] * d2 * inv + gb[t + 512]);
}

__global__ __launch_bounds__(256) void lnb_k(const float* __restrict__ x,
                                             const float* __restrict__ ga,
                                             const float* __restrict__ gb,
                                             unsigned short* __restrict__ out) {
  __shared__ float sm[8];
  int row = blockIdx.x;
  lnb_body(x + (size_t)row * DD, ga, gb, out + (size_t)row * DD, sm, threadIdx.x);
}

// two LN in one launch
__global__ __launch_bounds__(256) void lnb2_k(const float* __restrict__ x,
                                              const float* __restrict__ y,
                                              const float* __restrict__ gax,
                                              const float* __restrict__ gbx,
                                              const float* __restrict__ gay,
                                              const float* __restrict__ gby,
                                              unsigned short* __restrict__ ox,
                                              unsigned short* __restrict__ oy) {
  __shared__ float sm[8];
  int row = blockIdx.x;
  if (row < BB * SS)
    lnb_body(x + (size_t)row * DD, gax, gbx, ox + (size_t)row * DD, sm, threadIdx.x);
  else {
    row -= BB * SS;
    lnb_body(y + (size_t)row * DD, gay, gby, oy + (size_t)row * DD, sm, threadIdx.x);
  }
}

// ---------- 64k x 64n transpose tile: f32 [K][N] -> bf16 [N][K] ----------
__device__ __forceinline__ void tr_tile64(const float* __restrict__ s,
                                          unsigned short* __restrict__ d,
                                          int K, int N, int k0, int n0,
                                          float (*tl)[69], int t) {
#pragma unroll
  for (int i = 0; i < 4; i++) {
    int c = t + i * 256;
    int row = c >> 4, c4 = (c & 15) * 4;
    float4 v = *(const float4*)(s + (size_t)(k0 + row) * N + n0 + c4);
    tl[row][c4 + 0] = v.x; tl[row][c4 + 1] = v.y;
    tl[row][c4 + 2] = v.z; tl[row][c4 + 3] = v.w;
  }
  __syncthreads();
#pragma unroll
  for (int i = 0; i < 2; i++) {
    int c = t + i * 256;
    int n = c >> 3, kc = c & 7;
    us8 o;
#pragma unroll
    for (int j = 0; j < 8; j++) o[j] = f2bf(tl[kc * 8 + j][n]);
    *(us8*)(d + (size_t)(n0 + n) * K + k0 + kc * 8) = o;
  }
}

// ---- mega-upfront kernel: weight transposes (XCD-swizzled) + eob + emb/y + mask/bias ----
// [0,18816): transposes+eob (swizzled);  [18816,21888): embjoint;  [21888,22033): mask+bias.
__global__ __launch_bounds__(256) void wtx_k(
    const float* __restrict__ Wq, const float* __restrict__ Wk,
    const float* __restrict__ Wv, const float* __restrict__ Wo,
    const float* __restrict__ W1, const float* __restrict__ W2,
    const float* __restrict__ e_out,
    unsigned short* __restrict__ wqkv1A, unsigned short* __restrict__ wq2A,
    unsigned short* __restrict__ wkv2A, unsigned short* __restrict__ wqkv3A,
    unsigned short* __restrict__ wotA,
    unsigned short* __restrict__ w1tA, unsigned short* __restrict__ w2tA,
    unsigned short* __restrict__ eob,
    const int* __restrict__ trg, const float* __restrict__ emb,
    const float* __restrict__ alpha, const float* __restrict__ yp,
    float* __restrict__ x, float* __restrict__ y,
    int* __restrict__ rbuf,
    const float* __restrict__ bq, const float* __restrict__ bk,
    const float* __restrict__ bv, float* __restrict__ bqkv1,
    float* __restrict__ bkv2, float* __restrict__ bqkv3) {
  __shared__ float tl[64][69];
  const size_t M1 = (size_t)DD * DD;
  int rawbid = blockIdx.x;
  int t = threadIdx.x;
  if (rawbid < 18816) {
    int bid = (rawbid & 7) * 2352 + (rawbid >> 3);
    if (bid < 10368) {
      int mat = bid / 144, rem = bid % 144;
      int kt = rem / 12, nt = rem % 12;
      int l = mat / 12, m = mat % 12;
      size_t s3 = (size_t)l * 3 * M1;
      const float* s;
      unsigned short* d;
      switch (m) {
        case 0:  s = Wq + s3;          d = wqkv1A + l * 3 * M1;          break;
        case 1:  s = Wk + s3;          d = wqkv1A + l * 3 * M1 + M1;     break;
        case 2:  s = Wv + s3;          d = wqkv1A + l * 3 * M1 + 2 * M1; break;
        case 3:  s = Wq + s3 + M1;     d = wq2A + l * M1;                break;
        case 4:  s = Wk + s3 + M1;     d = wkv2A + l * 2 * M1;           break;
        case 5:  s = Wv + s3 + M1;     d = wkv2A + l * 2 * M1 + M1;      break;
        case 6:  s = Wq + s3 + 2 * M1; d = wqkv3A + l * 3 * M1;          break;
        case 7:  s = Wk + s3 + 2 * M1; d = wqkv3A + l * 3 * M1 + M1;     break;
        case 8:  s = Wv + s3 + 2 * M1; d = wqkv3A + l * 3 * M1 + 2 * M1; break;
        case 9:  s = Wo + s3;          d = wotA + l * 3 * M1;            break;
        case 10: s = Wo + s3 + M1;     d = wotA + l * 3 * M1 + M1;       break;
        default: s = Wo + s3 + 2 * M1; d = wotA + l * 3 * M1 + 2 * M1;   break;
      }
      tr_tile64(s, d, DD, DD, kt * 64, nt * 64, tl, t);
    } else if (bid < 13824) {
      int idx = bid - 10368;
      int l = idx / 576, rem = idx % 576;
      int kt = rem / 48, nt = rem % 48;
      tr_tile64(W1 + (size_t)l * DD * DFFF, w1tA + (size_t)l * DD * DFFF,
                DD, DFFF, kt * 64, nt * 64, tl, t);
    } else if (bid < 17280) {
      int idx = bid - 13824;
      int l = idx / 576, rem = idx % 576;
      int kt = rem / 12, nt = rem % 12;
      tr_tile64(W2 + (size_t)l * DFFF * DD, w2tA + (size_t)l * DFFF * DD,
                DFFF, DD, kt * 64, nt * 64, tl, t);
    } else {
      size_t base = (size_t)(bid - 17280) * 2048 + (size_t)t * 8;
      float4 a = *(const float4*)(e_out + base);
      float4 b = *(const float4*)(e_out + base + 4);
      us8 o;
      o[0] = f2bf(a.x); o[1] = f2bf(a.y); o[2] = f2bf(a.z); o[3] = f2bf(a.w);
      o[4] = f2bf(b.x); o[5] = f2bf(b.y); o[6] = f2bf(b.z); o[7] = f2bf(b.w);
      *(us8*)(eob + base) = o;
    }
  } else if (rawbid < 21888) {
    int z = rawbid - 18816;
    int half = (z >= 1536) ? 1 : 0;
    int idx = (z - half * 1536) * 256 + t;
    int c = idx % (DD / 4);
    int r = idx / (DD / 4);
    int s = r % SS;
    if (half == 0) {
      float al = alpha[0];
      float4 e = *(const float4*)(emb + (size_t)trg[r] * DD + c * 4);
      float coef = -logf(10000.0f) / (float)DD;
      float div0 = expf((float)(4 * c) * coef);
      float div1 = expf((float)(4 * c + 2) * coef);
      float s0, c0, s1, c1;
      sincosf((float)s * div0, &s0, &c0);
      sincosf((float)s * div1, &s1, &c1);
      float4 o;
      o.x = e.x + al * s0; o.y = e.y + al * c0;
      o.z = e.z + al * s1; o.w = e.w + al * c1;
      *(float4*)(x + (size_t)r * DD + c * 4) = o;
    } else {
      *(float4*)(y + (size_t)r * DD + c * 4) = *(const float4*)(yp + (size_t)s * DD + c * 4);
    }
  } else {
    int mbid = rawbid - 21888;
    if (mbid == 0) {
      __shared__ int first[BB];
      if (t < BB) first[t] = 0x7fffffff;
      __syncthreads();
      int b = t >> 4, p0 = (t & 15) * 8;
      int loc = 0x7fffffff;
#pragma unroll
      for (int i = 0; i < 8; i++) {
        if (trg[b * SS + p0 + i] == 0) { loc = p0 + i; break; }
      }
      atomicMin(&first[b], loc);
      __syncthreads();
      if (t == 0) {
        int cmin = 0x7fffffff;
        int cm[BB];
        for (int bb = 0; bb < BB; bb++) {
          int start = (first[bb] == 0x7fffffff) ? 0 : first[bb];
          int c = (start == 0) ? (SS + 1) : start;
          cmin = min(cmin, c);
          cm[bb] = cmin;
        }
        for (int bb = 0; bb < BB; bb++) rbuf[bb] = cm[min(bb, BB - 2)];
      }
      return;
    }
    int i = (mbid - 1) * 256 + t;
    if (i >= NLL * 6144) return;
    int l = i / 6144, j = i - l * 6144;
    if (j < 2304) {
      int s = j / 768, c = j - s * 768;
      const float* src = (s == 0) ? bq : (s == 1 ? bk : bv);
      bqkv1[l * 2304 + j] = src[(l * 3 + 0) * 768 + c];
    } else if (j < 3840) {
      int jj = j - 2304;
      int s = jj / 768, c = jj - s * 768;
      bkv2[l * 1536 + jj] = ((s == 0) ? bk : bv)[(l * 3 + 1) * 768 + c];
    } else {
      int jj = j - 3840;
      int s = jj / 768, c = jj - s * 768;
      const float* src = (s == 0) ? bq : (s == 1 ? bk : bv);
      bqkv3[l * 2304 + jj] = src[(l * 3 + 2) * 768 + c];
    }
  }
}

// ============ GEMM core macro: BK=64, two stacked 32-wide panels ============
#define GEMM_BODY64(BM, A, Bt, m0, n0, KK)                                    \
  constexpr int FM = (BM) / 32;                                               \
  constexpr int HB = (BM) / 2;                                                \
  int wave = t >> 6, lane = t & 63;                                           \
  int wm = wave >> 1, wn = wave & 1;                                          \
  int l15 = lane & 15, lhi = lane >> 4;                                       \
  f32x4 acc[FM][2] = {};                                                      \
  int aRow = t >> 2, aC8 = (t & 3) * 8;                                       \
  const unsigned short* Ab = (A) + (size_t)(m0) * (KK) + aC8;                 \
  const unsigned short* Bb = (Bt) + (size_t)(n0) * (KK) + aC8;                \
  int aOff0 = (wm * HB + l15) * 32 + lhi * 8;                                 \
  int bOff0 = (wn * 32 + l15) * 32 + lhi * 8;                                 \
  for (int k0 = 0; k0 < (KK); k0 += 64) {                                     \
    _Pragma("unroll")                                                         \
    for (int p = 0; p < 2; p++) {                                             \
      _Pragma("unroll")                                                       \
      for (int h = 0; h < (BM) / 64; h++)                                     \
        GLOADLDS16(Ab + (size_t)(h * 64 + aRow) * (KK) + k0 + p * 32,         \
                   As + p * ((BM) * 32) + h * 2048 + wave * 512);             \
      GLOADLDS16(Bb + (size_t)aRow * (KK) + k0 + p * 32,                      \
                 Bs + p * 2048 + wave * 512);                                 \
    }                                                                         \
    __syncthreads();                                                          \
    _Pragma("unroll")                                                         \
    for (int p = 0; p < 2; p++) {                                             \
      bf16x8 aF[FM], bF[2];                                                   \
      _Pragma("unroll")                                                       \
      for (int fm = 0; fm < FM; fm++)                                         \
        aF[fm] = *(const bf16x8*)(As + p * ((BM) * 32) + aOff0 + fm * 16 * 32);\
      _Pragma("unroll")                                                       \
      for (int fn = 0; fn < 2; fn++)                                          \
        bF[fn] = *(const bf16x8*)(Bs + p * 2048 + bOff0 + fn * 16 * 32);      \
      _Pragma("unroll")                                                       \
      for (int fm = 0; fm < FM; fm++)                                         \
        _Pragma("unroll")                                                     \
        for (int fn = 0; fn < 2; fn++)                                        \
          acc[fm][fn] = __builtin_amdgcn_mfma_f32_16x16x32_bf16(              \
              aF[fm], bF[fn], acc[fm][fn], 0, 0, 0);                          \
    }                                                                         \
    __syncthreads();                                                          \
  }                                                                           \
  int lcol = l15, lrow4 = lhi * 4;

// head-major store of one fragment column (4 rows) to hd with shift sh
__device__ __forceinline__ void hm_store(unsigned short* hd, int sh, int vt,
                                         int rowb, int colr, const f32x4& a,
                                         float bv) {
  int hh = colr >> 6, dd = colr & 63;
  int bb = rowb >> sh, ssb = rowb & ((1 << sh) - 1);
  if (vt) {
    size_t idx = (((size_t)bb * HH + hh) * 64 + dd) * (size_t)(1 << sh) + ssb;
    us4 pk;
#pragma unroll
    for (int r = 0; r < 4; r++) pk[r] = f2bf(a[r] + bv);
    *(us4*)(hd + idx) = pk;
  } else {
    size_t base = ((((size_t)bb * HH + hh) << sh) + ssb) * 64 + dd;
#pragma unroll
    for (int r = 0; r < 4; r++) hd[base + (size_t)r * 64] = f2bf(a[r] + bv);
  }
}

// ---------------- generic mgemm, BK=64 structure, BM template, K variable --------
template <int BM>
__global__ __launch_bounds__(256) void mgemm_k(
    const unsigned short* __restrict__ A0, const unsigned short* __restrict__ A1,
    const unsigned short* __restrict__ Bt, const float* __restrict__ bias,
    const float* __restrict__ res, void* __restrict__ C,
    unsigned short* __restrict__ hd0, unsigned short* __restrict__ hd1,
    unsigned short* __restrict__ hd2,
    int sh0, int sh1, int sh2, int M, int N, int K, int flags, int vtbits) {
  __shared__ unsigned short As[2 * BM * 32];
  __shared__ unsigned short Bs[2 * 64 * 32];
  int t = threadIdx.x;
  int m0 = blockIdx.y * BM, n0 = blockIdx.x * 64;
  int seg = n0 / 768;
  const unsigned short* A = (seg == 0) ? A0 : A1;
  GEMM_BODY64(BM, A, Bt, m0, n0, K)
  bool hm = (flags & 4) != 0;
  unsigned short* hd = nullptr;
  int sh = 0, segBase = seg * 768, vtseg = 0;
  if (hm) {
    hd = (seg == 0) ? hd0 : (seg == 1 ? hd1 : hd2);
    sh = (seg == 0) ? sh0 : (seg == 1 ? sh1 : sh2);
    vtseg = (vtbits >> seg) & 1;
  }
#pragma unroll
  for (int fm = 0; fm < FM; fm++) {
#pragma unroll
    for (int fn = 0; fn < 2; fn++) {
      int col = n0 + wn * 32 + fn * 16 + lcol;
      float bv = bias[col];
      int rowb = m0 + wm * HB + fm * 16 + lrow4;
      if (hm) {
        hm_store(hd, sh, vtseg, rowb, col - segBase, acc[fm][fn], bv);
      } else {
#pragma unroll
        for (int r = 0; r < 4; r++) {
          int row = rowb + r;
          float v = acc[fm][fn][r] + bv;
          size_t idx = (size_t)row * N + col;
          if (res) v += res[idx];
          if (flags & 1) v = fmaxf(v, 0.f);
          if (flags & 2) ((unsigned short*)C)[idx] = f2bf(v);
          else ((float*)C)[idx] = v;
        }
      }
    }
  }
}

// ---------------- all-layer KV2 projection: 128x64 tile, BK=64, XCD swizzle -----
__global__ __launch_bounds__(256) void kv2all_k(
    const unsigned short* __restrict__ eob, const unsigned short* __restrict__ wkv2A,
    const float* __restrict__ bkv2,
    unsigned short* __restrict__ khb2A, unsigned short* __restrict__ vthb2A) {
  __shared__ unsigned short As[2 * 128 * 32];
  __shared__ unsigned short Bs[2 * 64 * 32];
  const size_t M1 = (size_t)DD * DD;
  const size_t KVS = (size_t)BB * HH * SRCC * DKK;
  int t = threadIdx.x;
  int flat = blockIdx.x;                      // 4608 = 8 x 576
  int nf = (flat & 7) * 576 + (flat >> 3);    // bijective XCD chunking
  int bx = nf % 24;
  int rem = nf / 24;
  int by = rem & 31;
  int l = rem >> 5;
  int m0 = by * 128, n0 = bx * 64;
  const unsigned short* Bt = wkv2A + (size_t)l * 2 * M1;
  const float* bias = bkv2 + l * 1536;
  GEMM_BODY64(128, eob, Bt, m0, n0, 768)
  int seg = n0 / 768;
  unsigned short* hd = (seg == 0) ? khb2A + (size_t)l * KVS : vthb2A + (size_t)l * KVS;
  int segBase = seg * 768;
#pragma unroll
  for (int fm = 0; fm < FM; fm++) {
#pragma unroll
    for (int fn = 0; fn < 2; fn++) {
      int col = n0 + wn * 32 + fn * 16 + lcol;
      int rowb = m0 + wm * HB + fm * 16 + lrow4;
      hm_store(hd, 8, seg, rowb, col - segBase, acc[fm][fn], bias[col]);
    }
  }
}

// ---------------- batched qkv1 (x2b, 576 blocks) + q2 (y1b, 192 blocks) ----------
__global__ __launch_bounds__(256) void qkvq_k(
    const unsigned short* __restrict__ x2b, const unsigned short* __restrict__ y1b,
    const unsigned short* __restrict__ Bqkv, const unsigned short* __restrict__ Bq2,
    const float* __restrict__ bias1, const float* __restrict__ bias2,
    unsigned short* __restrict__ qhb, unsigned short* __restrict__ khb,
    unsigned short* __restrict__ vthb, unsigned short* __restrict__ qhb2) {
  __shared__ unsigned short As[2 * 128 * 32];
  __shared__ unsigned short Bs[2 * 64 * 32];
  int t = threadIdx.x;
  int bid = blockIdx.x;
  bool j1 = bid >= 576;
  int bx, by;
  const unsigned short *A, *Bt;
  const float* bias;
  if (!j1) { bx = bid % 36; by = bid / 36; A = x2b; Bt = Bqkv; bias = bias1; }
  else { int b2 = bid - 576; bx = b2 % 12; by = b2 / 12; A = y1b; Bt = Bq2; bias = bias2; }
  int m0 = by * 128, n0 = bx * 64;
  GEMM_BODY64(128, A, Bt, m0, n0, 768)
  int seg = j1 ? 0 : (n0 / 768);
  unsigned short* hd = j1 ? qhb2 : (seg == 0 ? qhb : (seg == 1 ? khb : vthb));
  int vt = (!j1 && seg == 2) ? 1 : 0;
  int segBase = seg * 768;
#pragma unroll
  for (int fm = 0; fm < FM; fm++) {
#pragma unroll
    for (int fn = 0; fn < 2; fn++) {
      int col = n0 + wn * 32 + fn * 16 + lcol;
      int rowb = m0 + wm * HB + fm * 16 + lrow4;
      hm_store(hd, 7, vt, rowb, col - segBase, acc[fm][fn], bias[col]);
    }
  }
}

// ---------------- batched wo1 (ctx1b -> x) + wo2 (ctx2b -> y), 768 blocks --------
__global__ __launch_bounds__(256) void wob_k(
    const unsigned short* __restrict__ ctx1b, const unsigned short* __restrict__ ctx2b,
    const unsigned short* __restrict__ Bt0, const unsigned short* __restrict__ Bt1,
    const float* __restrict__ bo0, const float* __restrict__ bo1,
    float* __restrict__ x, float* __restrict__ y) {
  __shared__ unsigned short As[2 * 64 * 32];
  __shared__ unsigned short Bs[2 * 64 * 32];
  int t = threadIdx.x;
  int bid = blockIdx.x;
  bool j1 = bid >= 384;
  int b2 = j1 ? bid - 384 : bid;
  int bx = b2 % 12, by = b2 / 12;
  const unsigned short* A = j1 ? ctx2b : ctx1b;
  const unsigned short* Bt = j1 ? Bt1 : Bt0;
  const float* bias = j1 ? bo1 : bo0;
  float* C = j1 ? y : x;
  int m0 = by * 64, n0 = bx * 64;
  GEMM_BODY64(64, A, Bt, m0, n0, 768)
#pragma unroll
  for (int fm = 0; fm < FM; fm++) {
#pragma unroll
    for (int fn = 0; fn < 2; fn++) {
      int col = n0 + wn * 32 + fn * 16 + lcol;
      float bv = bias[col];
      int rowb = m0 + wm * HB + fm * 16 + lrow4;
#pragma unroll
      for (int r = 0; r < 4; r++) {
        size_t idx = (size_t)(rowb + r) * DD + col;
        C[idx] += acc[fm][fn][r] + bv;
      }
    }
  }
}

// ---------------- MFMA flash attention body (R8-proven inner loops) --------------
template <int SK>
__device__ __forceinline__ void attn_body(
    const unsigned short* __restrict__ qh, const unsigned short* __restrict__ kh,
    const unsigned short* __restrict__ vth, unsigned short* __restrict__ ctxb,
    int mode, const int* __restrict__ rbuf, const int* __restrict__ smask,
    unsigned short* __restrict__ kvb, unsigned short* __restrict__ pbuf,
    int qhalf, int h, int b) {
  constexpr int NPH = SK / 128;
  constexpr int NF = SK / 16;
  int t = threadIdx.x;
  int wave = t >> 6, lane = t & 63;
  int l15 = lane & 15, lhi = lane >> 4;
  int qrow0 = qhalf * 64 + wave * 16;
  size_t bh = (size_t)b * HH + h;
  bf16x8 aQ[2];
#pragma unroll
  for (int ks = 0; ks < 2; ks++)
    aQ[ks] = *(const bf16x8*)(qh + (bh * SS + qrow0 + l15) * 64 + ks * 32 + lhi * 8);
  f32x4 accS[NF] = {};
  const unsigned short* kbase = kh + bh * SK * 64;
  for (int ph = 0; ph < NPH; ph++) {
    if (ph) __syncthreads();
    {
      int c0 = t * 4;
#pragma unroll
      for (int i = 0; i < 4; i++) {
        int c = c0 + i, row = c >> 3, co = (c & 7) * 8;
        *(us8*)&kvb[row * 72 + co] = *(const us8*)(kbase + (size_t)(ph * 128 + row) * 64 + co);
      }
    }
    __syncthreads();
#pragma unroll
    for (int kf = 0; kf < 8; kf++) {
      int gf = ph * 8 + kf;
#pragma unroll
      for (int ks = 0; ks < 2; ks++) {
        bf16x8 bK = *(const bf16x8*)(&kvb[(kf * 16 + l15) * 72 + ks * 32 + lhi * 8]);
        accS[gf] = __builtin_amdgcn_mfma_f32_16x16x32_bf16(aQ[ks], bK, accS[gf], 0, 0, 0);
      }
    }
  }
  int rcut = (mode == 0) ? rbuf[b] : 0;
#pragma unroll
  for (int r = 0; r < 4; r++) {
    int qg = qrow0 + lhi * 4 + r;
    float mx = -3.4e38f;
#pragma unroll
    for (int gf = 0; gf < NF; gf++) {
      int k = gf * 16 + l15;
      float s = accS[gf][r] * 0.125f;
      bool keep = true;
      if (mode == 0) keep = (k <= qg) && (qg < rcut);
      else if (mode == 1) keep = (smask[b * SRCC + k] != 0);
      s = keep ? s : -1e9f;
      accS[gf][r] = s;
      mx = fmaxf(mx, s);
    }
#pragma unroll
    for (int o = 1; o < 16; o <<= 1) mx = fmaxf(mx, __shfl_xor(mx, o));
    float sum = 0.f;
#pragma unroll
    for (int gf = 0; gf < NF; gf++) {
      float e = expf(accS[gf][r] - mx);
      accS[gf][r] = e;
      sum += e;
    }
#pragma unroll
    for (int o = 1; o < 16; o <<= 1) sum += __shfl_xor(sum, o);
    float rinv = 1.0f / sum;
#pragma unroll
    for (int gf = 0; gf < NF; gf++) accS[gf][r] *= rinv;
  }
#pragma unroll
  for (int gf = 0; gf < NF; gf++) {
#pragma unroll
    for (int r = 0; r < 4; r++) {
      int ql = wave * 16 + lhi * 4 + r;
      pbuf[ql * (SK + 8) + gf * 16 + l15] = f2bf(accS[gf][r]);
    }
  }
  __syncthreads();
  f32x4 accO[4] = {};
  const unsigned short* vbase = vth + bh * 64 * SK;
  for (int ph = 0; ph < NPH; ph++) {
    if (ph) __syncthreads();
    {
      int c0 = t * 4;
#pragma unroll
      for (int i = 0; i < 4; i++) {
        int c = c0 + i, row = c >> 4, co = (c & 15) * 8;
        *(us8*)&kvb[row * 136 + co] = *(const us8*)(vbase + (size_t)row * SK + ph * 128 + co);
      }
    }
    __syncthreads();
#pragma unroll
    for (int ks = 0; ks < 4; ks++) {
      bf16x8 aP = *(const bf16x8*)(&pbuf[(wave * 16 + l15) * (SK + 8) + ph * 128 + ks * 32 + lhi * 8]);
#pragma unroll
      for (int nf = 0; nf < 4; nf++) {
        bf16x8 bV = *(const bf16x8*)(&kvb[(nf * 16 + l15) * 136 + ks * 32 + lhi * 8]);
        accO[nf] = __builtin_amdgcn_mfma_f32_16x16x32_bf16(aP, bV, accO[nf], 0, 0, 0);
      }
    }
  }
#pragma unroll
  for (int nf = 0; nf < 4; nf++) {
#pragma unroll
    for (int r = 0; r < 4; r++) {
      int qg = qrow0 + lhi * 4 + r;
      ctxb[((size_t)b * SS + qg) * DD + h * 64 + nf * 16 + l15] = f2bf(accO[nf][r]);
    }
  }
}

// single-stream attention (step 8)
template <int SK>
__global__ __launch_bounds__(256) void attn3_k(const unsigned short* __restrict__ qh,
                                               const unsigned short* __restrict__ kh,
                                               const unsigned short* __restrict__ vth,
                                               unsigned short* __restrict__ ctxb, int mode,
                                               const int* __restrict__ rbuf,
                                               const int* __restrict__ smask) {
  __shared__ unsigned short kvb[128 * 72];
  __shared__ unsigned short pbuf[64 * (SK + 8)];
  attn_body<SK>(qh, kh, vth, ctxb, mode, rbuf, smask, kvb, pbuf,
                blockIdx.x, blockIdx.y, blockIdx.z);
}

// merged self(SK=128, mode0) + cross(SK=256, mode1): 768 blocks = 3/CU exactly.
__global__ __launch_bounds__(256) void attnboth_k(
    const unsigned short* __restrict__ qh1, const unsigned short* __restrict__ kh1,
    const unsigned short* __restrict__ vth1,
    const unsigned short* __restrict__ qh2, const unsigned short* __restrict__ kh2,
    const unsigned short* __restrict__ vth2,
    unsigned short* __restrict__ ctx1b, unsigned short* __restrict__ ctx2b,
    const int* __restrict__ rbuf, const int* __restrict__ smask) {
  __shared__ unsigned short kvb[128 * 72];
  __shared__ unsigned short pbuf[64 * (SRCC + 8)];
  int bid = blockIdx.x;
  if (bid < 384) {
    int qhalf = bid & 1, rest = bid >> 1;
    int h = rest % HH, b = rest / HH;
    attn_body<SRCC>(qh2, kh2, vth2, ctx2b, 1, nullptr, smask, kvb, pbuf, qhalf, h, b);
  } else {
    int b2 = bid - 384;
    int qhalf = b2 & 1, rest = b2 >> 1;
    int h = rest % HH, b = rest / HH;
    attn_body<SS>(qh1, kh1, vth1, ctx1b, 0, rbuf, nullptr, kvb, pbuf, qhalf, h, b);
  }
}

// ---------------- launch ----------------
extern "C" void kernel_launch(void* const* d_in, const int* in_sizes, int n_in,
                              void* d_out, int out_size, void* d_ws, size_t ws_size,
                              hipStream_t stream) {
  const int*   trg   = (const int*)d_in[0];
  const float* e_out = (const float*)d_in[1];
  const int*   smask = (const int*)d_in[2];
  const float* emb   = (const float*)d_in[3];
  const float* ypar  = (const float*)d_in[4];
  const float* alpha = (const float*)d_in[5];
  const float* Wq = (const float*)d_in[6];
  const float* Wk = (const float*)d_in[7];
  const float* Wv = (const float*)d_in[8];
  const float* Wo = (const float*)d_in[9];
  const float* bq = (const float*)d_in[10];
  const float* bk = (const float*)d_in[11];
  const float* bv = (const float*)d_in[12];
  const float* bo = (const float*)d_in[13];
  const float* W1 = (const float*)d_in[14];
  const float* b1 = (const float*)d_in[15];
  const float* W2 = (const float*)d_in[16];
  const float* b2 = (const float*)d_in[17];
  const float* lna = (const float*)d_in[18];
  const float* lnbp = (const float*)d_in[19];
  const float* fa = (const float*)d_in[20];
  const float* fb = (const float*)d_in[21];
  float* out = (float*)d_out;

  float* ws = (float*)d_ws;
  size_t off = 0;
  auto alloc = [&](size_t n) { float* p = ws + off; off += n; return p; };
  const size_t M1 = (size_t)DD * DD;
  const size_t KVS = (size_t)BB * HH * SRCC * DKK;
  int* rbuf  = (int*)alloc(64);
  float* x   = alloc((size_t)BB * SS * DD);
  float* y   = alloc((size_t)BB * SS * DD);
  float* bqkv1 = alloc((size_t)NLL * 2304);
  float* bkv2  = alloc((size_t)NLL * 1536);
  float* bqkv3 = alloc((size_t)NLL * 2304);
  unsigned short* qhb   = (unsigned short*)alloc((size_t)BB * HH * SS * DKK / 2);
  unsigned short* qhb2  = (unsigned short*)alloc((size_t)BB * HH * SS * DKK / 2);
  unsigned short* khb   = (unsigned short*)alloc((size_t)BB * HH * SS * DKK / 2);
  unsigned short* vthb  = (unsigned short*)alloc((size_t)BB * HH * SS * DKK / 2);
  unsigned short* khb2A  = (unsigned short*)alloc((size_t)NLL * KVS / 2);
  unsigned short* vthb2A = (unsigned short*)alloc((size_t)NLL * KVS / 2);
  unsigned short* x2b   = (unsigned short*)alloc((size_t)BB * SS * DD / 2);
  unsigned short* y3b   = (unsigned short*)alloc((size_t)BB * SS * DD / 2);
  unsigned short* ctx1b = (unsigned short*)alloc((size_t)BB * SS * DD / 2);
  unsigned short* ctx2b = (unsigned short*)alloc((size_t)BB * SS * DD / 2);
  unsigned short* midb  = (unsigned short*)alloc((size_t)BB * SS * DFFF / 2);
  unsigned short* eob   = (unsigned short*)alloc((size_t)BB * SRCC * DD / 2);
  unsigned short* wqkv1A = (unsigned short*)alloc((size_t)NLL * 3 * M1 / 2);
  unsigned short* wq2A   = (unsigned short*)alloc((size_t)NLL * M1 / 2);
  unsigned short* wkv2A  = (unsigned short*)alloc((size_t)NLL * 2 * M1 / 2);
  unsigned short* wqkv3A = (unsigned short*)alloc((size_t)NLL * 3 * M1 / 2);
  unsigned short* wotA   = (unsigned short*)alloc((size_t)NLL * 3 * M1 / 2);
  unsigned short* w1tA   = (unsigned short*)alloc((size_t)NLL * DD * DFFF / 2);
  unsigned short* w2tA   = (unsigned short*)alloc((size_t)NLL * DFFF * DD / 2);
  if (ws_size < off * sizeof(float)) return;

  // mega upfront kernel: transposes (XCD-swizzled) + eob + emb/y init + mask/bias
  wtx_k<<<22033, 256, 0, stream>>>(Wq, Wk, Wv, Wo, W1, W2, e_out,
                                   wqkv1A, wq2A, wkv2A, wqkv3A, wotA, w1tA, w2tA, eob,
                                   trg, emb, alpha, ypar, x, y, rbuf,
                                   bq, bk, bv, bqkv1, bkv2, bqkv3);
  kv2all_k<<<4608, 256, 0, stream>>>(eob, wkv2A, bkv2, khb2A, vthb2A);

  auto MG128 = [&](const unsigned short* A0, const unsigned short* A1, int M, int K,
                   const unsigned short* Bt, int N, const float* bias, const float* res,
                   void* C, unsigned short* h0, unsigned short* h1, unsigned short* h2,
                   int s0, int s1, int s2, int flags, int vtb) {
    mgemm_k<128><<<dim3(N / 64, M / 128), 256, 0, stream>>>(A0, A1, Bt, bias, res, C,
                                                            h0, h1, h2, s0, s1, s2, M, N, K, flags, vtb);
  };
  auto MG64 = [&](const unsigned short* A0, int M, int K,
                  const unsigned short* Bt, int N, const float* bias, const float* res,
                  void* C, unsigned short* h0, int s0, int flags, int vtb) {
    mgemm_k<64><<<dim3(N / 64, M / 64), 256, 0, stream>>>(A0, A0, Bt, bias, res, C,
                                                          h0, nullptr, nullptr, s0, 0, 0, M, N, K, flags, vtb);
  };
  const dim3 agrid(SS / 64, HH, BB);

  for (int l = 0; l < NLL; l++) {
    const float* lA = lna + (size_t)l * 5 * DD;
    const float* lB = lnbp + (size_t)l * 5 * DD;
    // 1) LN(x,slot0) + LN(y,slot1)
    lnb2_k<<<2 * BB * SS, 256, 0, stream>>>(x, y, lA, lB, lA + DD, lB + DD, x2b, y3b);
    // 2) qkv1 + q2 batched
    qkvq_k<<<768, 256, 0, stream>>>(x2b, y3b, wqkv1A + l * 3 * M1, wq2A + l * M1,
                                    bqkv1 + l * 2304, bq + ((size_t)l * 3 + 1) * DD,
                                    qhb, khb, vthb, qhb2);
    // 3+4) self-attn + cross-attn in ONE launch
    attnboth_k<<<768, 256, 0, stream>>>(qhb, khb, vthb,
                                        qhb2, khb2A + l * KVS, vthb2A + l * KVS,
                                        ctx1b, ctx2b, rbuf, smask);
    // 5) wo1 + wo2 batched (x += ..., y += ...)
    wob_k<<<768, 256, 0, stream>>>(ctx1b, ctx2b, wotA + l * 3 * M1, wotA + l * 3 * M1 + M1,
                                   bo + (size_t)l * 3 * DD, bo + ((size_t)l * 3 + 1) * DD, x, y);
    // 6) LN(x,slot2) + LN(y,slot3)
    lnb2_k<<<2 * BB * SS, 256, 0, stream>>>(x, y, lA + 2 * DD, lB + 2 * DD,
                                            lA + 3 * DD, lB + 3 * DD, x2b, y3b);
    // 7) qkv3 (segmented A: x2b | y3b)
    MG128(x2b, y3b, BB * SS, DD, wqkv3A + l * 3 * M1, 2304, bqkv3 + l * 2304, nullptr,
          nullptr, qhb, khb, vthb, 7, 7, 7, 4, 0b100);
    // 8) cross-attn x<-ln(y), no mask
    attn3_k<SS><<<agrid, 256, 0, stream>>>(qhb, khb, vthb, ctx1b, 2, nullptr, nullptr);
    // 9) wo3
    MG64(ctx1b, BB * SS, DD, wotA + l * 3 * M1 + 2 * M1, DD, bo + ((size_t)l * 3 + 2) * DD,
         x, x, nullptr, 0, 0, 0);
    // 10) LN(x,slot4)
    lnb_k<<<BB * SS, 256, 0, stream>>>(x, lA + 4 * DD, lB + 4 * DD, x2b);
    // 11) FFN1 (relu, bf16 out)
    MG128(x2b, x2b, BB * SS, DD, w1tA + (size_t)l * DD * DFFF, DFFF, b1 + (size_t)l * DFFF,
          nullptr, midb, nullptr, nullptr, nullptr, 0, 0, 0, 3, 0);
    // 12) FFN2 (K=3072, res x)
    MG64(midb, BB * SS, DFFF, w2tA + (size_t)l * DFFF * DD, DD, b2 + (size_t)l * DD, x, x,
         nullptr, 0, 0, 0);
  }
  ln_k<<<BB * SS, 256, 0, stream>>>(x, fa, fb, out);
}